// Round 3
// baseline (15.530 us; speedup 1.0000x reference)
//
#include <hip/hip_runtime.h>

// Filter-bank row offsets per order: OFF_i = sum_{j<i} C(60,j), OFF1 = 0.
#define OFF2 60
#define OFF3 1830
#define OFF4 36050
#define OFF5 523685
// Check: OFF5 + C(60,5) = 523685 + 5461512 = 5985197 = perms.

__global__ __launch_bounds__(256) void brutesolver_kernel(
        const int* __restrict__ x,      // [16] int32 in {0,1}
        const float* __restrict__ w,    // [perms] correlation weights
        const float* __restrict__ den_b,// [1] bias
        float* __restrict__ out) {      // [3*16] fp32
    // P[k][c] = sum_{v<c} C(59-v,k) = C(60,k+1) - C(60-c,k+1); P[0][c] = c.
    __shared__ int   P[5][61];
    __shared__ int   CB[16][6];         // C(n,k), n<=15
    __shared__ int   s_occ[16];
    __shared__ int   s_m;
    __shared__ int   sbuf[4944];        // max T = sum C(15,i), i=1..5 = 4943
    __shared__ float swave[4];

    const int tid = threadIdx.x;
    const int pix = blockIdx.x;         // 16 pixels
    const int py = pix >> 2, px = pix & 3;

    // ---- occupancy list via wave-0 ballot (sorted by tap code) ----
    if (tid < 64) {
        bool flag = false;
        if (tid < 60) {
            int iy = py + tid / 11 - 5;  // tap k -> (dy,dx)=(k/11,k%11)
            int ix = px + tid % 11 - 5;
            flag = (iy >= 0) && (iy < 4) && (ix >= 0) && (ix < 4) && (x[iy * 4 + ix] == 1);
        }
        unsigned long long mask = __ballot(flag);
        if (flag) s_occ[__popcll(mask & ((1ull << tid) - 1))] = tid;
        if (tid == 0) s_m = (int)__popcll(mask);
    }
    // ---- rank prefix tables (universe 60), parallel closed form ----
    if (tid <= 60) {
        long long n = 60 - tid;
        P[0][tid] = tid;
        P[1][tid] = 1770    - (int)(n * (n - 1) / 2);
        P[2][tid] = 34220   - (int)(n * (n - 1) * (n - 2) / 6);
        P[3][tid] = 487635  - (int)(n * (n - 1) * (n - 2) * (n - 3) / 24);
        P[4][tid] = 5461512 - (int)(n * (n - 1) * (n - 2) * (n - 3) * (n - 4) / 120);
    }
    if (tid < 16) {
        long long n = tid;
        CB[tid][0] = 1;
        CB[tid][1] = tid;
        CB[tid][2] = (int)(n * (n - 1) / 2);
        CB[tid][3] = (int)(n * (n - 1) * (n - 2) / 6);
        CB[tid][4] = (int)(n * (n - 1) * (n - 2) * (n - 3) / 24);
        CB[tid][5] = (int)(n * (n - 1) * (n - 2) * (n - 3) * (n - 4) / 120);
    }
    __syncthreads();

    const int m = s_m;
    const int nPairs = CB[m][2];
    const int nTrip  = CB[m][3];
    const int T = m + nPairs + nTrip + CB[m][4] + CB[m][5];

    // ---- phase 1: emit ranks at closed-form positions (no block scan) ----
    // singles occupy [0,m); pairs [m, m+nPairs); triple (a,b,c) segment at
    // m + nPairs + A1(a) + A2(a,b) + A3(b,c), segment size 1+t+C(t,2), t=m-1-c.
    if (tid < m) sbuf[tid] = s_occ[tid];                          // order-1 rank = c0

    if (tid < nPairs) {
        int q = tid, a = 0;
        while (CB[m - 1 - a][1] <= q) { q -= CB[m - 1 - a][1]; ++a; }
        int b = a + 1 + q;
        int c0 = s_occ[a], c1 = s_occ[b];
        sbuf[m + tid] = OFF2 + P[1][c0] + (c1 - c0 - 1);          // order-2
    }

    #pragma unroll
    for (int rep = 0; rep < 2; ++rep) {
        int j = tid + rep * 256;
        if (j < nTrip) {
            // decode lex triple j -> (a,b,c) over [0,m)
            int q = j, a = 0;
            while (CB[m - 1 - a][2] <= q) { q -= CB[m - 1 - a][2]; ++a; }
            int b = a + 1;
            while (CB[m - 1 - b][1] <= q) { q -= CB[m - 1 - b][1]; ++b; }
            int c = b + 1 + q;
            // closed-form segment base
            int A1 = (CB[m][3] - CB[m - a][3]) + (CB[m][4] - CB[m - a][4])
                   + (CB[m][5] - CB[m - a][5]);
            int A2 = (CB[m - 1 - a][2] - CB[m - b][2]) + (CB[m - 1 - a][3] - CB[m - b][3])
                   + (CB[m - 1 - a][4] - CB[m - b][4]);
            int A3 = (CB[m - 1 - b][1] - CB[m - c][1]) + (CB[m - 1 - b][2] - CB[m - c][2])
                   + (CB[m - 1 - b][3] - CB[m - c][3]);
            int pos = m + nPairs + A1 + A2 + A3;

            int c0 = s_occ[a], c1 = s_occ[b], c2 = s_occ[c];
            sbuf[pos++] = OFF3 + P[2][c0] + P[1][c1] - P[1][c0 + 1] + (c2 - c1 - 1);
            int b4 = P[3][c0] + P[2][c1] - P[2][c0 + 1] + P[1][c2] - P[1][c1 + 1];
            int b5 = P[4][c0] + P[3][c1] - P[3][c0 + 1] + P[2][c2] - P[2][c1 + 1];
            for (int di = c + 1; di < m; ++di) {
                int c3 = s_occ[di];
                sbuf[pos++] = OFF4 + b4 + (c3 - c2 - 1);
                int b5d = b5 + P[1][c3] - P[1][c2 + 1];
                for (int ei = di + 1; ei < m; ++ei) {
                    int c4 = s_occ[ei];
                    sbuf[pos++] = OFF5 + b5d + (c4 - c3 - 1);
                }
            }
        }
    }
    __syncthreads();

    // ---- phase 2: gather; 20 independent predicated loads, one drain ----
    float av[20];
    #pragma unroll
    for (int u = 0; u < 20; ++u) {
        av[u] = 0.f;
        int g = tid + 256 * u;
        if (g < T) av[u] = w[sbuf[g]];
    }
    float acc = 0.f;
    #pragma unroll
    for (int u = 0; u < 20; ++u) acc += av[u];

    // ---- wave shuffle reduce + cross-wave combine ----
    #pragma unroll
    for (int off = 32; off > 0; off >>= 1) acc += __shfl_xor(acc, off);
    if ((tid & 63) == 0) swave[tid >> 6] = acc;
    __syncthreads();
    if (tid == 0) {
        float y = swave[0] + swave[1] + swave[2] + swave[3] + den_b[0];
        out[pix]      = -100.0f;
        out[16 + pix] = -y;
        out[32 + pix] = y;
    }
}

extern "C" void kernel_launch(void* const* d_in, const int* in_sizes, int n_in,
                              void* d_out, int out_size, void* d_ws, size_t ws_size,
                              hipStream_t stream) {
    // inputs: 0=x(int32[16]) 1=filters(unused) 2=order_index(unused)
    //         3=w_corr(fp32[perms]) 4=den_w(unused) 5=den_b(fp32[1])
    const int*   x     = (const int*)d_in[0];
    const float* w     = (const float*)d_in[3];
    const float* den_b = (const float*)d_in[5];
    float* out = (float*)d_out;
    brutesolver_kernel<<<16, 256, 0, stream>>>(x, w, den_b, out);
}

// Round 4
// 11.515 us; speedup vs baseline: 1.3486x; 1.3486x over previous
//
#include <hip/hip_runtime.h>

// Filter-bank row offsets per order: OFF_i = sum_{j<i} C(60,j), OFF1 = 0.
#define OFF2 60
#define OFF3 1830
#define OFF4 36050
#define OFF5 523685
// Check: OFF5 + C(60,5) = 523685 + 5461512 = 5985197 = perms.

__global__ __launch_bounds__(256) void brutesolver_kernel(
        const int* __restrict__ x,      // [16] int32 in {0,1}
        const float* __restrict__ w,    // [perms] correlation weights
        const float* __restrict__ den_b,// [1] bias
        float* __restrict__ out) {      // [3*16] fp32
    // P[k][c] = sum_{v<c} C(59-v,k+1) ... rank prefix tables, k=1..4 stored at [k-1]
    __shared__ int   P1[61], P2[61], P3[61], P4[61];
    __shared__ int   CB[16][6];         // C(n,k), n<=15
    __shared__ int   s_occ[16];
    __shared__ int   s_m;
    __shared__ int   sbuf[4944];        // max T = sum C(15,i), i=1..5 = 4943
    __shared__ float swave[4];

    const int tid = threadIdx.x;
    const int pix = blockIdx.x;         // 16 pixels
    const int py = pix >> 2, px = pix & 3;

    // ---- occupancy list via wave-0 ballot (sorted by tap code) ----
    if (tid < 64) {
        bool flag = false;
        if (tid < 60) {
            int iy = py + tid / 11 - 5;  // tap k -> (dy,dx)=(k/11,k%11)
            int ix = px + tid % 11 - 5;
            flag = (iy >= 0) && (iy < 4) && (ix >= 0) && (ix < 4) && (x[iy * 4 + ix] == 1);
        }
        unsigned long long mask = __ballot(flag);
        if (flag) s_occ[__popcll(mask & ((1ull << tid) - 1))] = tid;
        if (tid == 0) s_m = (int)__popcll(mask);
    }
    // ---- rank prefix tables (universe 60): P_k[c] = C(60,k+1) - C(60-c,k+1) ----
    // products fit int32: 60*59*58*57*56 = 655,381,440 < 2^31
    if (tid <= 60) {
        int n = 60 - tid;
        P1[tid] = 1770    - n * (n - 1) / 2;
        P2[tid] = 34220   - n * (n - 1) * (n - 2) / 6;
        P3[tid] = 487635  - n * (n - 1) * (n - 2) * (n - 3) / 24;
        P4[tid] = 5461512 - (int)((long long)n * (n - 1) * (n - 2) * (n - 3) * (n - 4) / 120);
    }
    if (tid < 16) {
        int n = tid;
        CB[tid][0] = 1;
        CB[tid][1] = n;
        CB[tid][2] = n * (n - 1) / 2;
        CB[tid][3] = n * (n - 1) * (n - 2) / 6;
        CB[tid][4] = n * (n - 1) * (n - 2) * (n - 3) / 24;
        CB[tid][5] = n * (n - 1) * (n - 2) * (n - 3) * (n - 4) / 120;
    }
    __syncthreads();

    const int m = s_m;
    const int nPairs = CB[m][2];
    const int nTrip  = CB[m][3];
    const int T = m + nPairs + nTrip + CB[m][4] + CB[m][5];

    // ---- phase 1: emit ranks at closed-form positions ----
    if (tid < m) sbuf[tid] = s_occ[tid];                          // order-1 rank = c0

    if (tid < nPairs) {
        int q = tid, a = 0;
        while (CB[m - 1 - a][1] <= q) { q -= CB[m - 1 - a][1]; ++a; }
        int b = a + 1 + q;
        int c0 = s_occ[a], c1 = s_occ[b];
        sbuf[m + tid] = OFF2 + P1[c0] + (c1 - c0 - 1);            // order-2
    }

    #pragma unroll
    for (int rep = 0; rep < 2; ++rep) {
        int j = tid + rep * 256;
        if (j < nTrip) {
            // decode lex triple j -> (a,b,c) over [0,m)
            int q = j, a = 0;
            while (CB[m - 1 - a][2] <= q) { q -= CB[m - 1 - a][2]; ++a; }
            int b = a + 1;
            while (CB[m - 1 - b][1] <= q) { q -= CB[m - 1 - b][1]; ++b; }
            int c = b + 1 + q;
            // closed-form segment base within the triple-prefix ordering
            int A1 = (CB[m][3] - CB[m - a][3]) + (CB[m][4] - CB[m - a][4])
                   + (CB[m][5] - CB[m - a][5]);
            int A2 = (CB[m - 1 - a][2] - CB[m - b][2]) + (CB[m - 1 - a][3] - CB[m - b][3])
                   + (CB[m - 1 - a][4] - CB[m - b][4]);
            int A3 = (CB[m - 1 - b][1] - CB[m - c][1]) + (CB[m - 1 - b][2] - CB[m - c][2])
                   + (CB[m - 1 - b][3] - CB[m - c][3]);
            int pos = m + nPairs + A1 + A2 + A3;

            int c0 = s_occ[a], c1 = s_occ[b], c2 = s_occ[c];
            sbuf[pos++] = OFF3 + P2[c0] + P1[c1] - P1[c0 + 1] + (c2 - c1 - 1);
            int b4 = P3[c0] + P2[c1] - P2[c0 + 1] + P1[c2] - P1[c1 + 1];
            int b5 = P4[c0] + P3[c1] - P3[c0 + 1] + P2[c2] - P2[c1 + 1];
            for (int di = c + 1; di < m; ++di) {
                int c3 = s_occ[di];
                sbuf[pos++] = OFF4 + b4 + (c3 - c2 - 1);
                int b5d = b5 + P1[c3] - P1[c2 + 1];
                for (int ei = di + 1; ei < m; ++ei) {
                    int c4 = s_occ[ei];
                    sbuf[pos++] = OFF5 + b5d + (c4 - c3 - 1);
                }
            }
        }
    }
    __syncthreads();

    // ---- phase 2: gather. 4 predicated loads cover T<=1024 (m<=11, the
    // common case) in one latency drain; rare big-T loop for m>=12. ----
    float a0 = 0.f, a1 = 0.f, a2 = 0.f, a3 = 0.f;
    if (tid < T)       a0 = w[sbuf[tid]];
    if (tid + 256 < T) a1 = w[sbuf[tid + 256]];
    if (tid + 512 < T) a2 = w[sbuf[tid + 512]];
    if (tid + 768 < T) a3 = w[sbuf[tid + 768]];
    for (int g = tid + 1024; g < T; g += 1024) {        // rare
        a0 += w[sbuf[g]];
        if (g + 256 < T) a1 += w[sbuf[g + 256]];
        if (g + 512 < T) a2 += w[sbuf[g + 512]];
        if (g + 768 < T) a3 += w[sbuf[g + 768]];
    }
    float acc = (a0 + a1) + (a2 + a3);

    // ---- wave shuffle reduce + cross-wave combine ----
    #pragma unroll
    for (int off = 32; off > 0; off >>= 1) acc += __shfl_xor(acc, off);
    if ((tid & 63) == 0) swave[tid >> 6] = acc;
    __syncthreads();
    if (tid == 0) {
        float y = swave[0] + swave[1] + swave[2] + swave[3] + den_b[0];
        out[pix]      = -100.0f;
        out[16 + pix] = -y;
        out[32 + pix] = y;
    }
}

extern "C" void kernel_launch(void* const* d_in, const int* in_sizes, int n_in,
                              void* d_out, int out_size, void* d_ws, size_t ws_size,
                              hipStream_t stream) {
    // inputs: 0=x(int32[16]) 1=filters(unused) 2=order_index(unused)
    //         3=w_corr(fp32[perms]) 4=den_w(unused) 5=den_b(fp32[1])
    const int*   x     = (const int*)d_in[0];
    const float* w     = (const float*)d_in[3];
    const float* den_b = (const float*)d_in[5];
    float* out = (float*)d_out;
    brutesolver_kernel<<<16, 256, 0, stream>>>(x, w, den_b, out);
}